// Round 1
// baseline (3248.902 us; speedup 1.0000x reference)
//
#include <hip/hip_runtime.h>

// OT Sinkhorn loss, B=32 samples, N=512 points, OUT=56 (grid 3136), 100 iters.
// One 1024-thread block per sample; K = Ky (x) Kx separable, fp16 in LDS,
// v_dot2_f32_f16 inner products, fp64 final reductions.

#define NPTS   512
#define GRID   3136      // 56*56
#define OUTD   56
#define KYT_S  516       // KyT row stride (halfs): 1032B, 8B aligned, bank stride 258w -> 2-way free
#define KX_S   60        // Kx  row stride (halfs): 120B, 8B aligned, bank stride 30w
#define W_S    260       // W   row stride (halfs): 520B, 8B aligned, bank stride 130w

typedef _Float16 h2 __attribute__((ext_vector_type(2)));
typedef _Float16 h4 __attribute__((ext_vector_type(4)));

#define LOH(v) __builtin_shufflevector(v, v, 0, 1)
#define HIH(v) __builtin_shufflevector(v, v, 2, 3)

__device__ __forceinline__ float fdot2(h2 a, h2 b, float c) {
#if __has_builtin(__builtin_amdgcn_fdot2)
    return __builtin_amdgcn_fdot2(a, b, c, false);
#else
    return c + (float)a[0] * (float)b[0] + (float)a[1] * (float)b[1];
#endif
}

__device__ __forceinline__ float coordf(int k) {
    // cood = ((8k+4)/448)*2 - 1
    return (float)(8 * k + 4) * (1.0f / 224.0f) - 1.0f;
}

__device__ double blockReduce(double x, double* sRed, int tid) {
    #pragma unroll
    for (int o = 32; o > 0; o >>= 1) x += __shfl_down(x, o);
    int wid = tid >> 6;
    if ((tid & 63) == 0) sRed[wid] = x;
    __syncthreads();
    if (tid < 16) {
        x = sRed[tid];
        #pragma unroll
        for (int o = 8; o > 0; o >>= 1) x += __shfl_down(x, o);
    }
    __syncthreads();
    return x;  // valid on tid 0
}

extern "C" __global__ __launch_bounds__(1024, 1)
void ot_sinkhorn_kernel(const float* __restrict__ pred,
                        const float* __restrict__ normed,
                        const float* __restrict__ tpts,
                        double* __restrict__ ws) {
    extern __shared__ char smem[];
    double*    sRed = (double*)(smem);                 // 16 * 8   = 128
    float*     sU   = (float*)(smem + 128);            // 512 * 4  = 2048
    float*     sX   = (float*)(smem + 2176);           // 2048
    float*     sY   = (float*)(smem + 4224);           // 2048
    _Float16*  sKyT = (_Float16*)(smem + 6272);        // 56*516*2 = 57792 -> 64064
    _Float16*  sKx  = (_Float16*)(smem + 64064);       // 512*60*2 = 61440 -> 125504
    _Float16*  sW   = (_Float16*)(smem + 125504);      // 56*260*2 = 29120 -> 154624
    _Float16*  sVh  = (_Float16*)(smem + 154624);      // 3136*2   = 6272  -> 160896

    const int tid = threadIdx.x;
    const int s   = blockIdx.x;
    const float* tp = tpts + (size_t)s * NPTS * 2;
    const float* bv = normed + (size_t)s * GRID;  // b (normalized density)
    const float* sd = pred   + (size_t)s * GRID;  // source density (unnormalized)

    // ---------------- setup ----------------
    if (tid < NPTS) {
        float px = tp[tid * 2 + 0], py = tp[tid * 2 + 1];
        sX[tid] = px * (2.0f / 448.0f) - 1.0f;
        sY[tid] = py * (2.0f / 448.0f) - 1.0f;
        sU[tid] = 1.0f / (float)NPTS;
    }
    __syncthreads();
    for (int l = tid; l < NPTS * OUTD; l += 1024) {
        int n = l / OUTD, j = l - n * OUTD;
        float c  = coordf(j);
        float dx = sX[n] - c;
        float dy = sY[n] - c;
        sKx[n * KX_S + j]   = (_Float16)__expf(-dx * dx * 0.1f);
        sKyT[j * KYT_S + n] = (_Float16)__expf(-dy * dy * 0.1f);
    }
    __syncthreads();

    // GEMM-A tile assignment (tid < 784 = 28*28): strided 2x2 tiles
    const int aj = tid % 28, ai = tid / 28;  // ai in [0,36] but only tid<784 uses
    const int ja = aj, jb = aj + 28;
    const int ia = ai, ib = ai + 28;

    // ---------------- 100 Sinkhorn iterations ----------------
    for (int it = 0; it < 100; ++it) {
        float a00 = 0.f, a01 = 0.f, a10 = 0.f, a11 = 0.f;
        for (int pass = 0; pass < 2; ++pass) {
            const int nbase = pass * 256;
            __syncthreads();  // sU ready / prior sW reads done
            // build W[j][nh] = u[nbase+nh] * Kx[nbase+nh][j], fp16
            {
                const int l0 = tid * 14;  // 14336 = 1024*14
                #pragma unroll
                for (int q = 0; q < 14; ++q) {
                    int l  = l0 + q;
                    int j  = l >> 8;
                    int nh = l & 255;
                    float u  = sU[nbase + nh];
                    float kx = (float)sKx[(nbase + nh) * KX_S + j];
                    sW[j * W_S + nh] = (_Float16)(u * kx);
                }
            }
            __syncthreads();
            if (tid < 784) {
                const _Float16* wr0 = sW + ja * W_S;
                const _Float16* wr1 = sW + jb * W_S;
                const _Float16* kr0 = sKyT + ia * KYT_S + nbase;
                const _Float16* kr1 = sKyT + ib * KYT_S + nbase;
                #pragma unroll 2
                for (int nb = 0; nb < 256; nb += 4) {
                    h4 w0 = *(const h4*)(wr0 + nb);
                    h4 w1 = *(const h4*)(wr1 + nb);
                    h4 k0 = *(const h4*)(kr0 + nb);
                    h4 k1 = *(const h4*)(kr1 + nb);
                    h2 w0l = LOH(w0), w0h = HIH(w0);
                    h2 w1l = LOH(w1), w1h = HIH(w1);
                    h2 k0l = LOH(k0), k0h = HIH(k0);
                    h2 k1l = LOH(k1), k1h = HIH(k1);
                    a00 = fdot2(w0l, k0l, a00); a00 = fdot2(w0h, k0h, a00);
                    a01 = fdot2(w0l, k1l, a01); a01 = fdot2(w0h, k1h, a01);
                    a10 = fdot2(w1l, k0l, a10); a10 = fdot2(w1h, k0h, a10);
                    a11 = fdot2(w1l, k1l, a11); a11 = fdot2(w1h, k1h, a11);
                }
            }
        }
        // v = b / (u@K + 1e-16); a00=(ia,ja) a01=(ib,ja) a10=(ia,jb) a11=(ib,jb)
        if (tid < 784) {
            int maa = ia * OUTD + ja, mab = ia * OUTD + jb;
            int mba = ib * OUTD + ja, mbb = ib * OUTD + jb;
            sVh[maa] = (_Float16)(bv[maa] / (a00 + 1e-16f));
            sVh[mab] = (_Float16)(bv[mab] / (a10 + 1e-16f));
            sVh[mba] = (_Float16)(bv[mba] / (a01 + 1e-16f));
            sVh[mbb] = (_Float16)(bv[mbb] / (a11 + 1e-16f));
        }
        __syncthreads();
        // GEMM B: r[n] = sum_i Ky[n,i] * (sum_j Kx[n,j] V[i,j]); u = a/(r+1e-16)
        {
            const int n  = tid >> 1;
            const int ih = tid & 1;
            const _Float16* kxr = sKx + n * KX_S;
            h2 kx[28];
            #pragma unroll
            for (int c = 0; c < 14; ++c) {
                h4 t = *(const h4*)(kxr + c * 4);
                kx[2 * c]     = LOH(t);
                kx[2 * c + 1] = HIH(t);
            }
            float racc = 0.f;
            for (int ii = 0; ii < 28; ++ii) {
                const int i = ih * 28 + ii;
                const _Float16* vr = sVh + i * OUTD;
                float m1a = 0.f, m1b = 0.f;
                #pragma unroll
                for (int c = 0; c < 14; ++c) {
                    h4 t = *(const h4*)(vr + c * 4);
                    m1a = fdot2(kx[2 * c],     LOH(t), m1a);
                    m1b = fdot2(kx[2 * c + 1], HIH(t), m1b);
                }
                float ky = (float)sKyT[i * KYT_S + n];
                racc += ky * (m1a + m1b);
            }
            racc += __shfl_xor(racc, 1);
            if (ih == 0) sU[n] = (1.0f / (float)NPTS) / (racc + 1e-16f);
        }
        __syncthreads();
    }
    __syncthreads();

    // ---------------- epilogue ----------------
    // E1: ot = sum b*beta ; t1 = sum sd*beta ; sc = sum sd  (beta = 10*ln(v+1e-16))
    double ot = 0.0, t1 = 0.0, sc = 0.0;
    for (int m = tid; m < GRID; m += 1024) {
        float v    = (float)sVh[m];
        float beta = 10.0f * logf(v + 1e-16f);
        float sdm  = sd[m];
        ot += (double)(bv[m] * beta);
        t1 += (double)(sdm * beta);
        sc += (double)sdm;
    }
    ot = blockReduce(ot, sRed, tid);
    t1 = blockReduce(t1, sRed, tid);
    sc = blockReduce(sc, sRed, tid);

    // E2: wd = sum_{n,i,j} (ydist+xdist)*u[n]*Ky[n,i]*Kx[n,j]*v[i,j]
    double wdp = 0.0;
    {
        const int n  = tid >> 1;
        const int ih = tid & 1;
        const float xn = sX[n], yn = sY[n];
        const _Float16* kxr = sKx + n * KX_S;
        h2 kx[28], qx[28];
        #pragma unroll
        for (int c = 0; c < 28; ++c) {
            float k0 = (float)kxr[2 * c], k1 = (float)kxr[2 * c + 1];
            float c0 = coordf(2 * c), c1 = coordf(2 * c + 1);
            float d0 = xn - c0, d1 = xn - c1;
            h2 kk, qq;
            kk[0] = (_Float16)k0;            kk[1] = (_Float16)k1;
            qq[0] = (_Float16)(k0 * d0 * d0); qq[1] = (_Float16)(k1 * d1 * d1);
            kx[c] = kk; qx[c] = qq;
        }
        float wacc = 0.f;
        for (int ii = 0; ii < 28; ++ii) {
            const int i = ih * 28 + ii;
            const _Float16* vr = sVh + i * OUTD;
            float m1 = 0.f, m2 = 0.f;
            #pragma unroll
            for (int c = 0; c < 14; ++c) {
                h4 t = *(const h4*)(vr + c * 4);
                h2 tl = LOH(t), th = HIH(t);
                m1 = fdot2(kx[2 * c], tl, m1); m1 = fdot2(kx[2 * c + 1], th, m1);
                m2 = fdot2(qx[2 * c], tl, m2); m2 = fdot2(qx[2 * c + 1], th, m2);
            }
            float ci = coordf(i);
            float dy = yn - ci;
            float ky = (float)sKyT[i * KYT_S + n];
            wacc += ky * (dy * dy * m1 + m2);
        }
        wdp = (double)(sU[n] * wacc);
    }
    wdp = blockReduce(wdp, sRed, tid);

    if (tid == 0) {
        double denom = sc * sc + 1e-8;
        double c1 = sc / denom, c2 = t1 / denom;
        double loss = c1 * t1 - c2 * sc;  // mathematically 0
        ws[s * 3 + 0] = loss;
        ws[s * 3 + 1] = wdp;
        ws[s * 3 + 2] = ot;
    }
}

extern "C" __global__ void ot_reduce_kernel(const double* __restrict__ ws,
                                            float* __restrict__ out) {
    int k = threadIdx.x;
    if (k < 3) {
        double acc = 0.0;
        for (int b = 0; b < 32; ++b) acc += ws[b * 3 + k];
        out[k] = (float)acc;
    }
}

extern "C" void kernel_launch(void* const* d_in, const int* in_sizes, int n_in,
                              void* d_out, int out_size, void* d_ws, size_t ws_size,
                              hipStream_t stream) {
    const float* pred   = (const float*)d_in[0];
    const float* normed = (const float*)d_in[1];
    const float* tpts   = (const float*)d_in[2];
    double* ws = (double*)d_ws;

    ot_sinkhorn_kernel<<<dim3(32), dim3(1024), 160896, stream>>>(pred, normed, tpts, ws);
    ot_reduce_kernel<<<dim3(1), dim3(64), 0, stream>>>(ws, (float*)d_out);
}

// Round 2
// 870.136 us; speedup vs baseline: 3.7338x; 3.7338x over previous
//
#include <hip/hip_runtime.h>

// OT Sinkhorn, B=32, N=512, OUT=56 (pad 64), 100 iters — MFMA version.
// One 1024-thread block per sample. K = Ky (x) Kx separable.
// GEMM A: S[i][j] = sum_n (Ky[n,i]*u[n]) * Kx[n,j]   (A=WyT, B=KxT, K=512)
// GEMM B: M'[i][n] = sum_j V[i][j] * Kx[n,j]          (A=V,   B=KxN, K=64)
// r[n] = sum_i Ky[n,i]*M'[i][n] via in-lane exp-recompute + quad shuffles.

#define NPTS 512
#define GRID 3136
#define OUTD 56

typedef _Float16 h8 __attribute__((ext_vector_type(8)));
typedef float    f4 __attribute__((ext_vector_type(4)));

// LDS layout (bytes)
#define OFF_RED   0        // double[16]
#define OFF_Y     128      // float[512]
#define OFF_U     2176     // float[512]
#define OFF_V     4224     // f16 [64][72]                  (9216 B)
#define OFF_WYT   13440    // f16 [2][64][72] dbuf          (18432 B)
#define OFF_KXN   31872    // f16 [512][64] chunk-swizzled  (65536 B)
#define OFF_KXT   97408    // f16 [64][512] chunk-swizzled  (65536 B; reused as Kq)
#define LDS_TOTAL 162944

__device__ __forceinline__ float coordf(int k) {
    // ((8k+4)/448)*2 - 1
    return (float)(8 * k + 4) * (1.0f / 224.0f) - 1.0f;
}

// swizzled offsets (in halfs). chunk = 8 halfs = 16B.
__device__ __forceinline__ int kxn_off(int n, int j8) {   // [512][64], row n
    return n * 64 + ((j8 ^ (n & 7)) << 3);
}
__device__ __forceinline__ int kxt_off(int j, int n8) {   // [64][512], row j
    return j * 512 + ((n8 ^ (j & 7)) << 3);
}

__device__ double blockReduce(double x, double* sRed, int tid) {
    #pragma unroll
    for (int o = 32; o > 0; o >>= 1) x += __shfl_down(x, o);
    int wid = tid >> 6;
    if ((tid & 63) == 0) sRed[wid] = x;
    __syncthreads();
    if (tid < 16) {
        x = sRed[tid];
        #pragma unroll
        for (int o = 8; o > 0; o >>= 1) x += __shfl_down(x, o);
    }
    __syncthreads();
    return x;  // valid on tid 0
}

extern "C" __global__ __launch_bounds__(1024)
void ot_sinkhorn_mfma(const float* __restrict__ pred,
                      const float* __restrict__ normed,
                      const float* __restrict__ tpts,
                      double* __restrict__ ws)
{
    extern __shared__ char smem[];
    double*    sRed = (double*)(smem + OFF_RED);
    float*     sY   = (float*)(smem + OFF_Y);
    float*     sU   = (float*)(smem + OFF_U);
    _Float16*  sV   = (_Float16*)(smem + OFF_V);
    _Float16*  sWyT = (_Float16*)(smem + OFF_WYT);
    _Float16*  sKxN = (_Float16*)(smem + OFF_KXN);
    _Float16*  sKxT = (_Float16*)(smem + OFF_KXT);
    _Float16*  sKq  = sKxT;  // epilogue alias

    const int tid  = threadIdx.x;
    const int w    = tid >> 6;
    const int lane = tid & 63;
    const int quad = lane >> 4;
    const int l16  = lane & 15;
    const int s    = blockIdx.x;
    const float* tp = tpts  + (size_t)s * NPTS * 2;
    const float* bv = normed + (size_t)s * GRID;
    const float* sd = pred   + (size_t)s * GRID;

    // ---------------- setup ----------------
    if (tid < NPTS) {
        sY[tid] = tp[2 * tid + 1] * (2.0f / 448.0f) - 1.0f;
        sU[tid] = 1.0f / 512.0f;
    }
    {
        int n = tid >> 1, j0 = (tid & 1) * 32;
        float x = tp[2 * n] * (2.0f / 448.0f) - 1.0f;
        _Float16 kx[32];
        #pragma unroll
        for (int jj = 0; jj < 32; ++jj) {
            int j = j0 + jj;
            float d = x - coordf(j);
            kx[jj] = (j < OUTD) ? (_Float16)__expf(-d * d * 0.1f) : (_Float16)0.0f;
        }
        #pragma unroll
        for (int g = 0; g < 4; ++g) {
            h8 v;
            #pragma unroll
            for (int e = 0; e < 8; ++e) v[e] = kx[g * 8 + e];
            *(h8*)(sKxN + kxn_off(n, (j0 >> 3) + g)) = v;
        }
        #pragma unroll
        for (int jj = 0; jj < 32; ++jj) {
            int j = j0 + jj;
            sKxT[kxt_off(j, n >> 3) + (n & 7)] = kx[jj];
        }
    }
    __syncthreads();

    // GEMM A tile assignment (waves 0-3): 2x2 tiles of 16x16 over 64x64
    const int it0 = (w & 2);        // i-tile base (w=0,1 -> 0 ; w=2,3 -> 2)
    const int jt0 = (w & 1) * 2;    // j-tile base
    const int nt0 = w * 2;          // GEMM B: n-tile pair per wave

    const f4 fz = {0.f, 0.f, 0.f, 0.f};

    // ---------------- 100 Sinkhorn iterations ----------------
    for (int iter = 0; iter < 100; ++iter) {
        // ---- phase A: S = (Ky*u)^T Kx, K=512 in 8 chunks of 64, dbuf pipeline
        f4 accA[2][2];
        accA[0][0] = fz; accA[0][1] = fz; accA[1][0] = fz; accA[1][1] = fz;
        for (int c = 0; c <= 8; ++c) {
            if (w >= 8 && c < 8) {
                // build WyT chunk c: WyT[i][nl] = exp(-(y_n - c_i)^2/10)*u[n]
                int idx = tid - 512;
                int i = idx >> 3, nl0 = (idx & 7) * 8;
                int ng = c * 64 + nl0;
                float ci = coordf(i);
                h8 outv;
                #pragma unroll
                for (int e = 0; e < 8; ++e) {
                    float d = sY[ng + e] - ci;
                    outv[e] = (_Float16)(__expf(-d * d * 0.1f) * sU[ng + e]);
                }
                *(h8*)(sWyT + (c & 1) * (64 * 72) + i * 72 + nl0) = outv;
            }
            if (w < 4 && c > 0) {
                const _Float16* wy = sWyT + ((c - 1) & 1) * (64 * 72);
                int kg0 = (c - 1) * 64;
                #pragma unroll
                for (int ks = 0; ks < 2; ++ks) {
                    int kl = ks * 32 + quad * 8;
                    h8 af[2], bf[2];
                    #pragma unroll
                    for (int a = 0; a < 2; ++a)
                        af[a] = *(const h8*)(wy + ((it0 + a) * 16 + l16) * 72 + kl);
                    #pragma unroll
                    for (int b = 0; b < 2; ++b) {
                        int j = (jt0 + b) * 16 + l16;
                        bf[b] = *(const h8*)(sKxT + kxt_off(j, (kg0 + kl) >> 3));
                    }
                    #pragma unroll
                    for (int a = 0; a < 2; ++a)
                        #pragma unroll
                        for (int b = 0; b < 2; ++b)
                            accA[a][b] = __builtin_amdgcn_mfma_f32_16x16x32_f16(
                                af[a], bf[b], accA[a][b], 0, 0, 0);
                }
            }
            __syncthreads();
        }
        // ---- v-step: v = b/(S+eps), pad -> 0, store f16 (waves 0-3)
        if (w < 4) {
            #pragma unroll
            for (int a = 0; a < 2; ++a)
                #pragma unroll
                for (int b = 0; b < 2; ++b)
                    #pragma unroll
                    for (int r = 0; r < 4; ++r) {
                        int i = (it0 + a) * 16 + quad * 4 + r;
                        int j = (jt0 + b) * 16 + l16;
                        float v = 0.f;
                        if (i < OUTD && j < OUTD)
                            v = bv[i * OUTD + j] / (accA[a][b][r] + 1e-16f);
                        sV[i * 72 + j] = (_Float16)v;
                    }
        }
        __syncthreads();
        // ---- phase B: M'[i][n] = sum_j V[i][j]*Kx[n][j] (all 16 waves)
        f4 accB[2][4];
        #pragma unroll
        for (int ntl = 0; ntl < 2; ++ntl)
            #pragma unroll
            for (int t = 0; t < 4; ++t) accB[ntl][t] = fz;
        #pragma unroll
        for (int ks = 0; ks < 2; ++ks) {
            int kl = ks * 32 + quad * 8;
            h8 af[4];
            #pragma unroll
            for (int t = 0; t < 4; ++t)
                af[t] = *(const h8*)(sV + (t * 16 + l16) * 72 + kl);
            #pragma unroll
            for (int ntl = 0; ntl < 2; ++ntl) {
                int n = (nt0 + ntl) * 16 + l16;
                h8 bf = *(const h8*)(sKxN + kxn_off(n, kl >> 3));
                #pragma unroll
                for (int t = 0; t < 4; ++t)
                    accB[ntl][t] = __builtin_amdgcn_mfma_f32_16x16x32_f16(
                        af[t], bf, accB[ntl][t], 0, 0, 0);
            }
        }
        // ---- r-step: r[n] = sum_i Ky[n,i]*M'[i][n]; u = a/(r+eps)
        #pragma unroll
        for (int ntl = 0; ntl < 2; ++ntl) {
            int n = (nt0 + ntl) * 16 + l16;
            float y = sY[n];
            float p = 0.f;
            #pragma unroll
            for (int t = 0; t < 4; ++t)
                #pragma unroll
                for (int r = 0; r < 4; ++r) {
                    int i = t * 16 + quad * 4 + r;
                    float d = y - coordf(i);
                    p += __expf(-d * d * 0.1f) * accB[ntl][t][r];
                }
            p += __shfl_xor(p, 16);
            p += __shfl_xor(p, 32);
            if (lane < 16) sU[n] = (1.0f / 512.0f) / (p + 1e-16f);
        }
        __syncthreads();
    }

    // ---------------- epilogue ----------------
    // E1: ot, t1, sc from beta = 10*ln(v+1e-16)
    double ot = 0.0, t1 = 0.0, sc = 0.0;
    for (int m = tid; m < GRID; m += 1024) {
        int i = m / OUTD, j = m - i * OUTD;
        float v = (float)sV[i * 72 + j];
        float beta = 10.0f * logf(v + 1e-16f);
        float sdm = sd[m];
        ot += (double)(bv[m] * beta);
        t1 += (double)(sdm * beta);
        sc += (double)sdm;
    }
    ot = blockReduce(ot, sRed, tid);
    t1 = blockReduce(t1, sRed, tid);
    sc = blockReduce(sc, sRed, tid);

    // build Kq[n][j] = Kx[n][j]*(x_n - c_j)^2 into KxT region (dead)
    {
        int n = tid >> 1, j0 = (tid & 1) * 32;
        float x = tp[2 * n] * (2.0f / 448.0f) - 1.0f;
        #pragma unroll
        for (int g = 0; g < 4; ++g) {
            h8 kxv = *(const h8*)(sKxN + kxn_off(n, (j0 >> 3) + g));
            h8 kqv;
            #pragma unroll
            for (int e = 0; e < 8; ++e) {
                float d = x - coordf(j0 + g * 8 + e);
                kqv[e] = (_Float16)((float)kxv[e] * d * d);
            }
            *(h8*)(sKq + kxn_off(n, (j0 >> 3) + g)) = kqv;
        }
    }
    __syncthreads();

    // E2: wd = sum_n u[n] sum_i Ky[n,i]*(dy^2*M1'[i][n] + M2'[i][n])
    double wdd = 0.0;
    #pragma unroll
    for (int ntl = 0; ntl < 2; ++ntl) {
        int n = (nt0 + ntl) * 16 + l16;
        f4 m1[4], m2[4];
        #pragma unroll
        for (int t = 0; t < 4; ++t) { m1[t] = fz; m2[t] = fz; }
        #pragma unroll
        for (int ks = 0; ks < 2; ++ks) {
            int kl = ks * 32 + quad * 8;
            h8 af[4];
            #pragma unroll
            for (int t = 0; t < 4; ++t)
                af[t] = *(const h8*)(sV + (t * 16 + l16) * 72 + kl);
            h8 b1 = *(const h8*)(sKxN + kxn_off(n, kl >> 3));
            h8 b2 = *(const h8*)(sKq  + kxn_off(n, kl >> 3));
            #pragma unroll
            for (int t = 0; t < 4; ++t) {
                m1[t] = __builtin_amdgcn_mfma_f32_16x16x32_f16(af[t], b1, m1[t], 0, 0, 0);
                m2[t] = __builtin_amdgcn_mfma_f32_16x16x32_f16(af[t], b2, m2[t], 0, 0, 0);
            }
        }
        float y = sY[n], u = sU[n];
        float acc = 0.f;
        #pragma unroll
        for (int t = 0; t < 4; ++t)
            #pragma unroll
            for (int r = 0; r < 4; ++r) {
                int i = t * 16 + quad * 4 + r;
                float d = y - coordf(i);
                float ky = __expf(-d * d * 0.1f);
                acc += ky * (d * d * m1[t][r] + m2[t][r]);
            }
        wdd += (double)(u * acc);
    }
    wdd = blockReduce(wdd, sRed, tid);

    if (tid == 0) {
        double denom = sc * sc + 1e-8;
        ws[s * 3 + 0] = (sc / denom) * t1 - (t1 / denom) * sc;  // ~0
        ws[s * 3 + 1] = wdd;
        ws[s * 3 + 2] = ot;
    }
}

extern "C" __global__ void ot_reduce_kernel(const double* __restrict__ ws,
                                            float* __restrict__ out) {
    int k = threadIdx.x;
    if (k < 3) {
        double acc = 0.0;
        for (int b = 0; b < 32; ++b) acc += ws[b * 3 + k];
        out[k] = (float)acc;
    }
}

extern "C" void kernel_launch(void* const* d_in, const int* in_sizes, int n_in,
                              void* d_out, int out_size, void* d_ws, size_t ws_size,
                              hipStream_t stream) {
    const float* pred   = (const float*)d_in[0];
    const float* normed = (const float*)d_in[1];
    const float* tpts   = (const float*)d_in[2];
    double* ws = (double*)d_ws;

    ot_sinkhorn_mfma<<<dim3(32), dim3(1024), LDS_TOTAL, stream>>>(pred, normed, tpts, ws);
    ot_reduce_kernel<<<dim3(1), dim3(64), 0, stream>>>(ws, (float*)d_out);
}

// Round 3
// 500.498 us; speedup vs baseline: 6.4913x; 1.7385x over previous
//
#include <hip/hip_runtime.h>

// OT Sinkhorn, B=32, N=512, OUT=56 (pad 64), 100 iters — MFMA, exp-free inner loop.
// Phase A: S[i][j] = sum_n (Ky[i,n]*u[n]) * Kx[j,n]   A=KyT(LDS)*u(bcast), B=KxT(LDS), K=512
// Phase B: T'[j][n] = sum_i V[i,j] * Ky[n,i]          A=VT(LDS),           B=Ky regs,  K=64
// r[n] = sum_j Kx[n,j]*T'[j][n] via reg-cached Kx slice + 2 shuffles.

#define NPTS 512
#define GRID 3136
#define OUTD 56

typedef _Float16 h8  __attribute__((ext_vector_type(8)));
typedef _Float16 h4v __attribute__((ext_vector_type(4)));
typedef float    f4  __attribute__((ext_vector_type(4)));

#define OFF_RED 0          // double[16]                 128 B
#define OFF_Y   128        // float[512]                2048 B
#define OFF_X   2176       // float[512]                2048 B
#define OFF_UH  4224       // f16[512]                  1024 B
#define OFF_VT  5248       // f16 [64][72]              9216 B
#define OFF_KYT 14464      // f16 [64][512] swizzled   65536 B
#define OFF_KXT 80000      // f16 [64][512] swizzled   65536 B
#define LDS_TOTAL 145536

__device__ __forceinline__ float coordf(int k) {
    // ((8k+4)/448)*2 - 1
    return (float)(8 * k + 4) * (1.0f / 224.0f) - 1.0f;
}

// swizzled offset (halfs) into a [64][512] f16 table; c8 = 8-half chunk idx 0..63
__device__ __forceinline__ int tr_off(int row, int c8) {
    return row * 512 + ((c8 ^ (row & 7)) << 3);
}

__device__ double blockReduce(double x, double* sRed, int tid) {
    #pragma unroll
    for (int o = 32; o > 0; o >>= 1) x += __shfl_down(x, o);
    int wid = tid >> 6;
    if ((tid & 63) == 0) sRed[wid] = x;
    __syncthreads();
    if (tid < 16) {
        x = sRed[tid];
        #pragma unroll
        for (int o = 8; o > 0; o >>= 1) x += __shfl_down(x, o);
    }
    __syncthreads();
    return x;  // valid on tid 0
}

extern "C" __global__ __launch_bounds__(1024)
void ot_sinkhorn_mfma(const float* __restrict__ pred,
                      const float* __restrict__ normed,
                      const float* __restrict__ tpts,
                      double* __restrict__ ws)
{
    extern __shared__ char smem[];
    double*    sRed = (double*)(smem + OFF_RED);
    float*     sY   = (float*)(smem + OFF_Y);
    float*     sX   = (float*)(smem + OFF_X);
    _Float16*  sUh  = (_Float16*)(smem + OFF_UH);
    _Float16*  sVT  = (_Float16*)(smem + OFF_VT);
    _Float16*  sKyT = (_Float16*)(smem + OFF_KYT);
    _Float16*  sKxT = (_Float16*)(smem + OFF_KXT);

    const int tid  = threadIdx.x;
    const int w    = tid >> 6;
    const int lane = tid & 63;
    const int quad = lane >> 4;
    const int l16  = lane & 15;
    const int s    = blockIdx.x;
    const float* tp = tpts  + (size_t)s * NPTS * 2;
    const float* bv = normed + (size_t)s * GRID;
    const float* sd = pred   + (size_t)s * GRID;

    // ---------------- setup ----------------
    if (tid < NPTS) {
        sX[tid]  = tp[2 * tid + 0] * (2.0f / 448.0f) - 1.0f;
        sY[tid]  = tp[2 * tid + 1] * (2.0f / 448.0f) - 1.0f;
        sUh[tid] = (_Float16)(1.0f / 512.0f);
    }
    __syncthreads();

    // static tables KxT[j][n], KyT[i][n] (rows >=56 zeroed)
    {
        int n = tid >> 1, j0 = (tid & 1) * 32;
        float x = sX[n], y = sY[n];
        #pragma unroll
        for (int jj = 0; jj < 32; ++jj) {
            int j = j0 + jj;
            float c = coordf(j);
            float dx = x - c, dy = y - c;
            _Float16 kx = (j < OUTD) ? (_Float16)__expf(-dx * dx * 0.1f) : (_Float16)0.0f;
            _Float16 ky = (j < OUTD) ? (_Float16)__expf(-dy * dy * 0.1f) : (_Float16)0.0f;
            sKxT[tr_off(j, n >> 3) + (n & 7)] = kx;
            sKyT[tr_off(j, n >> 3) + (n & 7)] = ky;
        }
    }

    // register caches (static): Ky B-fragment slice + Kx r-step slice
    const int nt0 = w * 2;
    h8 kyA[2][2];   // [ntl][ks][e] = Ky[n][i], n=(nt0+ntl)*16+l16, i=ks*32+quad*8+e
    #pragma unroll
    for (int ntl = 0; ntl < 2; ++ntl) {
        int n = (nt0 + ntl) * 16 + l16;
        float y = sY[n];
        #pragma unroll
        for (int ks = 0; ks < 2; ++ks)
            #pragma unroll
            for (int e = 0; e < 8; ++e) {
                int i = ks * 32 + quad * 8 + e;
                float d = y - coordf(i);
                kyA[ntl][ks][e] = (i < OUTD) ? (_Float16)__expf(-d * d * 0.1f)
                                             : (_Float16)0.0f;
            }
    }
    h8 kxR[2][2];   // [ntl][jt>>1][(jt&1)*4+r] = Kx[n][j], j=jt*16+quad*4+r
    #pragma unroll
    for (int ntl = 0; ntl < 2; ++ntl) {
        int n = (nt0 + ntl) * 16 + l16;
        float x = sX[n];
        #pragma unroll
        for (int jt = 0; jt < 4; ++jt)
            #pragma unroll
            for (int r = 0; r < 4; ++r) {
                int j = jt * 16 + quad * 4 + r;
                float d = x - coordf(j);
                kxR[ntl][jt >> 1][(jt & 1) * 4 + r] =
                    (j < OUTD) ? (_Float16)__expf(-d * d * 0.1f) : (_Float16)0.0f;
            }
    }
    __syncthreads();

    const int it0 = (w & 2);        // phase-A i-tile base (waves 0-3)
    const int jt0 = (w & 1) * 2;    // phase-A j-tile base
    const f4 fz = {0.f, 0.f, 0.f, 0.f};

    // ---------------- 100 Sinkhorn iterations ----------------
    for (int iter = 0; iter < 100; ++iter) {
        if (w < 4) {
            // ---- phase A: 2x2 16-tiles per wave, K=512
            f4 accA[2][2];
            accA[0][0] = fz; accA[0][1] = fz; accA[1][0] = fz; accA[1][1] = fz;
            #pragma unroll 2
            for (int c = 0; c < 8; ++c) {
                #pragma unroll
                for (int ks = 0; ks < 2; ++ks) {
                    int kg = c * 64 + ks * 32;
                    int c8 = (kg >> 3) + quad;
                    h8 uf  = *(const h8*)(sUh + kg + quad * 8);       // broadcast
                    h8 af0 = *(const h8*)(sKyT + tr_off((it0 + 0) * 16 + l16, c8));
                    h8 af1 = *(const h8*)(sKyT + tr_off((it0 + 1) * 16 + l16, c8));
                    af0 *= uf; af1 *= uf;
                    h8 bf0 = *(const h8*)(sKxT + tr_off((jt0 + 0) * 16 + l16, c8));
                    h8 bf1 = *(const h8*)(sKxT + tr_off((jt0 + 1) * 16 + l16, c8));
                    accA[0][0] = __builtin_amdgcn_mfma_f32_16x16x32_f16(af0, bf0, accA[0][0], 0, 0, 0);
                    accA[0][1] = __builtin_amdgcn_mfma_f32_16x16x32_f16(af0, bf1, accA[0][1], 0, 0, 0);
                    accA[1][0] = __builtin_amdgcn_mfma_f32_16x16x32_f16(af1, bf0, accA[1][0], 0, 0, 0);
                    accA[1][1] = __builtin_amdgcn_mfma_f32_16x16x32_f16(af1, bf1, accA[1][1], 0, 0, 0);
                }
            }
            // ---- v-step: v = b/(S+eps); write transposed VT[j][i] as b64 packs
            #pragma unroll
            for (int a = 0; a < 2; ++a)
                #pragma unroll
                for (int b = 0; b < 2; ++b) {
                    int ib = (it0 + a) * 16 + quad * 4;
                    int j  = (jt0 + b) * 16 + l16;
                    h4v vv;
                    #pragma unroll
                    for (int r = 0; r < 4; ++r) {
                        int i = ib + r;
                        float v = 0.f;
                        if (i < OUTD && j < OUTD)
                            v = bv[i * OUTD + j] / (accA[a][b][r] + 1e-16f);
                        vv[r] = (_Float16)v;
                    }
                    *(h4v*)(sVT + j * 72 + ib) = vv;
                }
        }
        __syncthreads();

        // ---- phase B: T'[j][n], all 16 waves, 4 j-tiles x 2 n-tiles each
        f4 acc[2][4];
        #pragma unroll
        for (int ntl = 0; ntl < 2; ++ntl)
            #pragma unroll
            for (int jt = 0; jt < 4; ++jt) acc[ntl][jt] = fz;
        #pragma unroll
        for (int ks = 0; ks < 2; ++ks) {
            int qoff = ks * 32 + quad * 8;
            h8 af[4];
            #pragma unroll
            for (int jt = 0; jt < 4; ++jt)
                af[jt] = *(const h8*)(sVT + (jt * 16 + l16) * 72 + qoff);
            #pragma unroll
            for (int ntl = 0; ntl < 2; ++ntl)
                #pragma unroll
                for (int jt = 0; jt < 4; ++jt)
                    acc[ntl][jt] = __builtin_amdgcn_mfma_f32_16x16x32_f16(
                        af[jt], kyA[ntl][ks], acc[ntl][jt], 0, 0, 0);
        }
        // ---- r-step: r[n] = sum_j Kx[n,j]*T'[j][n]; u = a/(r+eps)
        {
            float rs0 = 0.f, rs1 = 0.f;
            #pragma unroll
            for (int jt = 0; jt < 4; ++jt)
                #pragma unroll
                for (int r = 0; r < 4; ++r) {
                    int e = (jt & 1) * 4 + r, hh = jt >> 1;
                    rs0 += (float)kxR[0][hh][e] * acc[0][jt][r];
                    rs1 += (float)kxR[1][hh][e] * acc[1][jt][r];
                }
            rs0 += __shfl_xor(rs0, 16); rs0 += __shfl_xor(rs0, 32);
            rs1 += __shfl_xor(rs1, 16); rs1 += __shfl_xor(rs1, 32);
            if (quad < 2) {
                float rr = quad ? rs1 : rs0;
                int n = (nt0 + quad) * 16 + l16;
                sUh[n] = (_Float16)((1.0f / 512.0f) / (rr + 1e-16f));
            }
        }
        __syncthreads();
    }

    // ---------------- epilogue ----------------
    // E1: ot, t1, sc from beta = 10*ln(v+1e-16)
    double ot = 0.0, t1d = 0.0, sc = 0.0;
    for (int m = tid; m < GRID; m += 1024) {
        int i = m / OUTD, j = m - i * OUTD;
        float v = (float)sVT[j * 72 + i];
        float beta = 10.0f * logf(v + 1e-16f);
        float sdm = sd[m];
        ot  += (double)(bv[m] * beta);
        t1d += (double)(sdm * beta);
        sc  += (double)sdm;
    }
    ot  = blockReduce(ot, sRed, tid);
    t1d = blockReduce(t1d, sRed, tid);
    sc  = blockReduce(sc, sRed, tid);

    // E2: wd = sum_n u_n sum_j [ Kx*T2' + Kx*dx^2*T' ]
    double wdd = 0.0;
    {
        h8 kyQ[2][2];
        #pragma unroll
        for (int ntl = 0; ntl < 2; ++ntl) {
            int n = (nt0 + ntl) * 16 + l16;
            float y = sY[n];
            #pragma unroll
            for (int ks = 0; ks < 2; ++ks)
                #pragma unroll
                for (int e = 0; e < 8; ++e) {
                    int i = ks * 32 + quad * 8 + e;
                    float d = y - coordf(i);
                    kyQ[ntl][ks][e] = (_Float16)((float)kyA[ntl][ks][e] * d * d);
                }
        }
        #pragma unroll
        for (int ntl = 0; ntl < 2; ++ntl) {
            f4 tA[4], tQ[4];
            #pragma unroll
            for (int jt = 0; jt < 4; ++jt) { tA[jt] = fz; tQ[jt] = fz; }
            #pragma unroll
            for (int ks = 0; ks < 2; ++ks) {
                int qoff = ks * 32 + quad * 8;
                #pragma unroll
                for (int jt = 0; jt < 4; ++jt) {
                    h8 af = *(const h8*)(sVT + (jt * 16 + l16) * 72 + qoff);
                    tA[jt] = __builtin_amdgcn_mfma_f32_16x16x32_f16(af, kyA[ntl][ks], tA[jt], 0, 0, 0);
                    tQ[jt] = __builtin_amdgcn_mfma_f32_16x16x32_f16(af, kyQ[ntl][ks], tQ[jt], 0, 0, 0);
                }
            }
            int n = (nt0 + ntl) * 16 + l16;
            float x = sX[n];
            float u = (float)sUh[n];
            float ssum = 0.f;
            #pragma unroll
            for (int jt = 0; jt < 4; ++jt)
                #pragma unroll
                for (int r = 0; r < 4; ++r) {
                    int j = jt * 16 + quad * 4 + r;
                    float kx = (float)kxR[ntl][jt >> 1][(jt & 1) * 4 + r];
                    float dx = x - coordf(j);
                    ssum += kx * tQ[jt][r] + (kx * dx * dx) * tA[jt][r];
                }
            wdd += (double)(u * ssum);
        }
    }
    wdd = blockReduce(wdd, sRed, tid);

    if (tid == 0) {
        double denom = sc * sc + 1e-8;
        ws[s * 3 + 0] = (sc / denom) * t1d - (t1d / denom) * sc;  // ~0
        ws[s * 3 + 1] = wdd;
        ws[s * 3 + 2] = ot;
    }
}

extern "C" __global__ void ot_reduce_kernel(const double* __restrict__ ws,
                                            float* __restrict__ out) {
    int k = threadIdx.x;
    if (k < 3) {
        double acc = 0.0;
        for (int b = 0; b < 32; ++b) acc += ws[b * 3 + k];
        out[k] = (float)acc;
    }
}

extern "C" void kernel_launch(void* const* d_in, const int* in_sizes, int n_in,
                              void* d_out, int out_size, void* d_ws, size_t ws_size,
                              hipStream_t stream) {
    const float* pred   = (const float*)d_in[0];
    const float* normed = (const float*)d_in[1];
    const float* tpts   = (const float*)d_in[2];
    double* ws = (double*)d_ws;

    ot_sinkhorn_mfma<<<dim3(32), dim3(1024), LDS_TOTAL, stream>>>(pred, normed, tpts, ws);
    ot_reduce_kernel<<<dim3(1), dim3(64), 0, stream>>>(ws, (float*)d_out);
}